// Round 1
// baseline (1250.033 us; speedup 1.0000x reference)
//
#include <hip/hip_runtime.h>

namespace {

constexpr int kB = 512, kD = 64, kP = 16, kT = 500, kH = 128;
constexpr int kKZ = 80;              // D + P (z width)
constexpr int kRows = 16;            // batch rows per block (one MFMA M-tile)
constexpr int kBlocks = kB / kRows;  // 32
constexpr int kThreads = 512;        // 8 waves -> 2 waves/SIMD (latency hiding)

// LDS row strides (u16 elements). Writes use a k-chunk XOR-2 swizzle for
// rows >= 8 so ds_write_b16 lands 2-way instead of 4-way.
constexpr int Z0S = 104;  // z planes: 12 used 16B chunks + pad
constexpr int HS = 136;   // h planes: 16 chunks + pad
constexpr int YS = 68;    // yb fp32 row stride

typedef __attribute__((ext_vector_type(8))) short short8;
typedef __attribute__((ext_vector_type(4))) float float4v;

__device__ __forceinline__ float bf2f(unsigned short u) {
  union { unsigned int i; float f; } v;
  v.i = ((unsigned int)u) << 16;
  return v.f;
}
__device__ __forceinline__ unsigned short f2bf(float f) {  // RNE
  union { float f; unsigned int i; } v;
  v.f = f;
  return (unsigned short)((v.i + 0x7FFFu + ((v.i >> 16) & 1u)) >> 16);
}
__device__ __forceinline__ void split_bf(float x, unsigned short& hi, unsigned short& lo) {
  hi = f2bf(x);
  lo = f2bf(x - bf2f(hi));
}
#if __has_builtin(__builtin_amdgcn_cvt_pk_bf16_f32)
__device__ __forceinline__ unsigned int pk_bf16(float a, float b) {
  auto v = __builtin_amdgcn_cvt_pk_bf16_f32(a, b);
  unsigned int u;
  __builtin_memcpy(&u, &v, 4);
  return u;
}
#else
__device__ __forceinline__ unsigned int pk_bf16(float a, float b) {
  return (unsigned int)f2bf(a) | ((unsigned int)f2bf(b) << 16);
}
#endif
__device__ __forceinline__ unsigned short f2bf1(float x) {  // 1-instr RNE round
  return (unsigned short)pk_bf16(x, x);
}
__device__ __forceinline__ void split2(float x, unsigned short& hi, unsigned short& lo) {
  unsigned int uh = pk_bf16(x, x);
  float hif;
  { unsigned int tb = uh << 16; __builtin_memcpy(&hif, &tb, 4); }
  hi = (unsigned short)uh;
  lo = (unsigned short)pk_bf16(x - hif, x - hif);
}
__device__ __forceinline__ float fast_tanh(float x) {
  // 1 - 2/(e^{2x}+1): exact saturation both ends, no NaN, 5 VALU.
  float e = __builtin_amdgcn_exp2f(x * 2.885390081777927f);  // 2*log2(e)
  return 1.0f - 2.0f * __builtin_amdgcn_rcpf(e + 1.0f);
}

// MFMA 16x16x32 bf16 layouts (gfx950):
//   A[m][k]: m = lane&15, k = (lane>>4)*8 + j
//   B[k][n]: n = lane&15, k = (lane>>4)*8 + j
//   C/D[m][n]: n = lane&15, m = (lane>>4)*4 + reg
__global__ __launch_bounds__(kThreads, 2) void node_kernel(
    const float* __restrict__ xg, const float* __restrict__ pg,
    const float* __restrict__ w0g, const float* __restrict__ b0g,
    const float* __restrict__ w1g, const float* __restrict__ b1g,
    const float* __restrict__ w2g, const float* __restrict__ b2g,
    float* __restrict__ outg) {
  __shared__ __align__(16) unsigned short zh[kRows * Z0S];
  __shared__ __align__(16) unsigned short zl[kRows * Z0S];
  __shared__ __align__(16) unsigned short h0h[kRows * HS];
  __shared__ __align__(16) unsigned short h1h[kRows * HS];
  __shared__ __align__(16) float yb[8][kRows * YS];  // 8-step output staging

  const int tid = threadIdx.x;
  const int wv = tid >> 6;    // wave 0..7: owns 16 cols of L0/L1; waves 0-3 own L2
  const int lane = tid & 63;
  const int l15 = lane & 15;
  const int quad = lane >> 4;
  const int brow = blockIdx.x * kRows;
  const int rswz = (quad & 2) ? 2 : 0;  // writer chunk swizzle (rows = quad*4+r)
  const int asw = (l15 & 8) ? 2 : 0;    // A-frag reader chunk swizzle (row = l15)

  const int col01 = wv * 16 + l15;        // L0/L1 output column of this wave
  const int colL2 = (wv & 3) * 16 + l15;  // L2 column (waves 4-7 duplicate loads, unused)

  // ---- persistent split-weight fragments in VGPRs ----
  // w0: z-part kt=0,1 (K 0..63); p-part kt=2 (K 64..95, zero-padded >=80)
  short8 w0fh[2], w0fl[2], w0pfh, w0pfl, w1fh[4], w1fl[4], w2fh[4], w2fl[4];
  {
    const int k0q = quad * 8;
#pragma unroll
    for (int kt = 0; kt < 2; ++kt) {
      short8 vh, vl;
#pragma unroll
      for (int j = 0; j < 8; ++j) {
        unsigned short hi, lo;
        split_bf(w0g[(kt * 32 + k0q + j) * kH + col01], hi, lo);
        vh[j] = (short)hi; vl[j] = (short)lo;
      }
      w0fh[kt] = vh; w0fl[kt] = vl;
    }
    {
      short8 vh, vl;
#pragma unroll
      for (int j = 0; j < 8; ++j) {
        int k = 64 + k0q + j;
        unsigned short hi = 0, lo = 0;
        if (k < kKZ) split_bf(w0g[k * kH + col01], hi, lo);
        vh[j] = (short)hi; vl[j] = (short)lo;
      }
      w0pfh = vh; w0pfl = vl;
    }
#pragma unroll
    for (int kt = 0; kt < 4; ++kt) {
      short8 vh, vl;
#pragma unroll
      for (int j = 0; j < 8; ++j) {
        unsigned short hi, lo;
        split_bf(w1g[(kt * 32 + k0q + j) * kH + col01], hi, lo);
        vh[j] = (short)hi; vl[j] = (short)lo;
      }
      w1fh[kt] = vh; w1fl[kt] = vl;
    }
#pragma unroll
    for (int kt = 0; kt < 4; ++kt) {
      short8 vh, vl;
#pragma unroll
      for (int j = 0; j < 8; ++j) {
        unsigned short hi, lo;
        split_bf(w2g[(kt * 32 + k0q + j) * kD + colL2], hi, lo);
        vh[j] = (short)hi; vl[j] = (short)lo;
      }
      w2fh[kt] = vh; w2fl[kt] = vl;
    }
  }
  const float bias0 = b0g[col01];
  const float bias1 = b1g[col01];
  const float bias2 = b2g[colL2];

  // ---- per-lane fp32 state registers (waves 0-3; C/D layout rows quad*4+r) ----
  float stR[4], d1R[4];
#pragma unroll
  for (int r = 0; r < 4; ++r)
    stR[r] = xg[((size_t)(brow + quad * 4 + r) * kD + colL2) * kT];  // t = 0

  // ---- LDS init: z state cols (swizzled), zero p/pad chunks 8..12 ----
  for (int idx = tid; idx < kRows * kD; idx += kThreads) {
    int r = idx >> 6, c = idx & 63;
    float xv = xg[((size_t)(brow + r) * kD + c) * kT];
    unsigned short hi, lo;
    split_bf(xv, hi, lo);
    int off = r * Z0S + ((((c >> 3) ^ ((r & 8) ? 2 : 0)) << 3) | (c & 7));
    zh[off] = hi;
    zl[off] = lo;
  }
  for (int idx = tid; idx < kRows * 40; idx += kThreads) {  // physical cols 64..103
    int r = idx / 40, c = idx % 40;
    zh[r * Z0S + kD + c] = 0;
    zl[r * Z0S + kD + c] = 0;
  }
  // p staging lives on waves 4-7 (idle during L2/z-write -> off critical path)
  const int tpi = tid & 255;
  const int prow = (tpi >> 4) & 15, ppp = tpi & 15;  // 16x16 map (tid>=256)
  const size_t pbase = ((size_t)(brow + prow) * kP + ppp) * kT;
  const int poff = prow * Z0S + ((((8 + (ppp >> 3)) ^ ((prow & 8) ? 2 : 0)) << 3) | (ppp & 7));
  float pv = (tid >= 256) ? pg[pbase] : 0.0f;  // p[..., 0]
  __syncthreads();

  for (int t = 0; t < kT; ++t) {
    if (tid >= 256) {  // p columns of z (swizzled chunk)
      unsigned short hi, lo;
      split2(pv, hi, lo);
      zh[poff] = hi;
      zl[poff] = lo;
    }
    __syncthreads();  // z complete (state cols from prev step, p now)

    float pvn = 0.0f;
    if (tid >= 256 && t + 1 < kT) pvn = pg[pbase + t + 1];  // prefetch

    if ((t & 7) == 0 && t) {  // burst previous 8-step output tile
      const int t0 = t - 8;
#pragma unroll
      for (int q2 = 0; q2 < 2; ++q2) {
        int idx = tid + q2 * kThreads;
        int r = idx >> 6, c = idx & 63;
        float v[8];
#pragma unroll
        for (int s = 0; s < 8; ++s) v[s] = yb[s][r * YS + c];
        float* dst = outg + ((size_t)(brow + r) * kD + c) * kT + t0;  // 16B-aligned
        float4v vlo = {v[0], v[1], v[2], v[3]}, vhi = {v[4], v[5], v[6], v[7]};
        *(float4v*)(dst) = vlo;
        *(float4v*)(dst + 4) = vhi;
      }
    }

    // ---- step-invariant p-term: bias0 + z[64:96]*W0p (both Heun evals) ----
    // Kept in a SEPARATE accumulator (psum): eval-0's L0 state MFMAs no longer
    // depend on these three MFMAs; psum joins only at the final add.
    float4v psum;
    {
      const int off = l15 * Z0S + (((8 + quad) ^ asw) << 3);
      short8 aph = *(const short8*)&zh[off];
      short8 apl = *(const short8*)&zl[off];
      float4v z4 = {0.f, 0.f, 0.f, 0.f};
      float4v b4 = {bias0, bias0, bias0, bias0};
      float4v phh = __builtin_amdgcn_mfma_f32_16x16x32_bf16(aph, w0pfh, b4, 0, 0, 0);
      float4v phl = __builtin_amdgcn_mfma_f32_16x16x32_bf16(aph, w0pfl, z4, 0, 0, 0);
      float4v plh = __builtin_amdgcn_mfma_f32_16x16x32_bf16(apl, w0pfh, z4, 0, 0, 0);
      psum = phh + (phl + plh);
    }

#pragma unroll
    for (int ev = 0; ev < 2; ++ev) {  // Heun: eval1 at c, eval2 at c+d1
      // ---- L0: z[16x64] @ W0z[64x16] + cached p-term; full split ----
      // 3 parallel chains of depth 2 (was depth 3 chained through p-term).
      short8 a0h[2], a0l[2];
#pragma unroll
      for (int kt = 0; kt < 2; ++kt) {
        const int off = l15 * Z0S + (((kt * 4 + quad) ^ asw) << 3);
        a0h[kt] = *(const short8*)&zh[off];
        a0l[kt] = *(const short8*)&zl[off];
      }
      {
        float4v z4 = {0.f, 0.f, 0.f, 0.f};
        float4v ahh = __builtin_amdgcn_mfma_f32_16x16x32_bf16(a0h[0], w0fh[0], z4, 0, 0, 0);
        ahh = __builtin_amdgcn_mfma_f32_16x16x32_bf16(a0h[1], w0fh[1], ahh, 0, 0, 0);
        float4v ahl = __builtin_amdgcn_mfma_f32_16x16x32_bf16(a0h[0], w0fl[0], z4, 0, 0, 0);
        ahl = __builtin_amdgcn_mfma_f32_16x16x32_bf16(a0h[1], w0fl[1], ahl, 0, 0, 0);
        float4v alh = __builtin_amdgcn_mfma_f32_16x16x32_bf16(a0l[0], w0fh[0], z4, 0, 0, 0);
        alh = __builtin_amdgcn_mfma_f32_16x16x32_bf16(a0l[1], w0fh[1], alh, 0, 0, 0);
        float4v ac = (ahh + ahl) + (alh + psum);
        const int cb = wv * 2 + (l15 >> 3);
        const int off = (((cb ^ rswz) << 3) | (l15 & 7));
#pragma unroll
        for (int r = 0; r < 4; ++r)
          h0h[(quad * 4 + r) * HS + off] = f2bf1(fast_tanh(ac[r]));
      }
      __syncthreads();
      // ---- L1: h0[16x128] @ W1[128x16], hi-activation + w-lo correction ----
      // 4 parallel chains of depth 2 (was 2 chains of depth 4).
      short8 a1h[4];
#pragma unroll
      for (int kt = 0; kt < 4; ++kt) {
        const int off = l15 * HS + (((kt * 4 + quad) ^ asw) << 3);
        a1h[kt] = *(const short8*)&h0h[off];
      }
      {
        float4v z4 = {0.f, 0.f, 0.f, 0.f};
        float4v b4 = {bias1, bias1, bias1, bias1};
        float4v hh0 = __builtin_amdgcn_mfma_f32_16x16x32_bf16(a1h[0], w1fh[0], b4, 0, 0, 0);
        hh0 = __builtin_amdgcn_mfma_f32_16x16x32_bf16(a1h[1], w1fh[1], hh0, 0, 0, 0);
        float4v hh1 = __builtin_amdgcn_mfma_f32_16x16x32_bf16(a1h[2], w1fh[2], z4, 0, 0, 0);
        hh1 = __builtin_amdgcn_mfma_f32_16x16x32_bf16(a1h[3], w1fh[3], hh1, 0, 0, 0);
        float4v hl0 = __builtin_amdgcn_mfma_f32_16x16x32_bf16(a1h[0], w1fl[0], z4, 0, 0, 0);
        hl0 = __builtin_amdgcn_mfma_f32_16x16x32_bf16(a1h[1], w1fl[1], hl0, 0, 0, 0);
        float4v hl1 = __builtin_amdgcn_mfma_f32_16x16x32_bf16(a1h[2], w1fl[2], z4, 0, 0, 0);
        hl1 = __builtin_amdgcn_mfma_f32_16x16x32_bf16(a1h[3], w1fl[3], hl1, 0, 0, 0);
        float4v ac = (hh0 + hh1) + (hl0 + hl1);
        const int cb = wv * 2 + (l15 >> 3);
        const int off = (((cb ^ rswz) << 3) | (l15 & 7));
#pragma unroll
        for (int r = 0; r < 4; ++r)
          h1h[(quad * 4 + r) * HS + off] = f2bf1(fast_tanh(ac[r]));
      }
      __syncthreads();
      // ---- L2: h1[16x128] @ W2[128x16] on waves 0-3 only ----
      float4v ac;
      if (wv < 4) {
        short8 a2h[4];
#pragma unroll
        for (int kt = 0; kt < 4; ++kt) {
          const int off = l15 * HS + (((kt * 4 + quad) ^ asw) << 3);
          a2h[kt] = *(const short8*)&h1h[off];
        }
        float4v z4 = {0.f, 0.f, 0.f, 0.f};
        float4v b4 = {bias2, bias2, bias2, bias2};
        float4v hh0 = __builtin_amdgcn_mfma_f32_16x16x32_bf16(a2h[0], w2fh[0], b4, 0, 0, 0);
        hh0 = __builtin_amdgcn_mfma_f32_16x16x32_bf16(a2h[1], w2fh[1], hh0, 0, 0, 0);
        float4v hh1 = __builtin_amdgcn_mfma_f32_16x16x32_bf16(a2h[2], w2fh[2], z4, 0, 0, 0);
        hh1 = __builtin_amdgcn_mfma_f32_16x16x32_bf16(a2h[3], w2fh[3], hh1, 0, 0, 0);
        float4v hl0 = __builtin_amdgcn_mfma_f32_16x16x32_bf16(a2h[0], w2fl[0], z4, 0, 0, 0);
        hl0 = __builtin_amdgcn_mfma_f32_16x16x32_bf16(a2h[1], w2fl[1], hl0, 0, 0, 0);
        float4v hl1 = __builtin_amdgcn_mfma_f32_16x16x32_bf16(a2h[2], w2fl[2], z4, 0, 0, 0);
        hl1 = __builtin_amdgcn_mfma_f32_16x16x32_bf16(a2h[3], w2fl[3], hl1, 0, 0, 0);
        ac = (hh0 + hh1) + (hl0 + hl1);
      }

      const int zcb = (wv & 3) * 2 + (l15 >> 3);
      const int zoff = (((zcb ^ rswz) << 3) | (l15 & 7));
      if (ev == 0) {
        if (wv < 4) {
#pragma unroll
          for (int r = 0; r < 4; ++r) {
            d1R[r] = ac[r];
            float xi = stR[r] + ac[r];  // dt = 1
            unsigned short hi, lo;
            split2(xi, hi, lo);
            zh[(quad * 4 + r) * Z0S + zoff] = hi;
            zl[(quad * 4 + r) * Z0S + zoff] = lo;
          }
        }
        __syncthreads();  // xi visible to all waves for eval2's L0
      } else {
        if (wv < 4) {
#pragma unroll
          for (int r = 0; r < 4; ++r) {
            float c = stR[r];
            float nx = c + 0.5f * (ac[r] + d1R[r]);
            yb[t & 7][(quad * 4 + r) * YS + colL2] = c;  // emit PREVIOUS state
            stR[r] = nx;
            unsigned short hi, lo;
            split2(nx, hi, lo);
            zh[(quad * 4 + r) * Z0S + zoff] = hi;
            zl[(quad * 4 + r) * Z0S + zoff] = lo;
          }
        }
        // no barrier: next iteration's top sync covers these stores
      }
    }
    pv = pvn;
  }
  __syncthreads();
  // tail flush: t = 496..499 (slots 0..3 of the last tile)
  {
    const int t0 = (kT / 8) * 8;  // 496
#pragma unroll
    for (int q2 = 0; q2 < 2; ++q2) {
      int idx = tid + q2 * kThreads;
      int r = idx >> 6, c = idx & 63;
      float v[4];
#pragma unroll
      for (int s = 0; s < 4; ++s) v[s] = yb[s][r * YS + c];
      float* dst = outg + ((size_t)(brow + r) * kD + c) * kT + t0;
      float4v vv = {v[0], v[1], v[2], v[3]};
      *(float4v*)(dst) = vv;
    }
  }
}

}  // namespace

extern "C" void kernel_launch(void* const* d_in, const int* in_sizes, int n_in,
                              void* d_out, int out_size, void* d_ws, size_t ws_size,
                              hipStream_t stream) {
  const float* xg = (const float*)d_in[0];   // x [512,64,500]
  const float* pg = (const float*)d_in[1];   // p [512,16,500]
  // d_in[2] = i_ext (unused by Simple_MLP)
  const float* w0g = (const float*)d_in[3];  // W0 [80,128]
  const float* b0g = (const float*)d_in[4];  // b0 [128]
  const float* w1g = (const float*)d_in[5];  // W1 [128,128]
  const float* b1g = (const float*)d_in[6];  // b1 [128]
  const float* w2g = (const float*)d_in[7];  // W2 [128,64]
  const float* b2g = (const float*)d_in[8];  // b2 [64]
  float* outg = (float*)d_out;               // [512,64,500] fp32

  hipLaunchKernelGGL(node_kernel, dim3(kBlocks), dim3(kThreads), 0, stream,
                     xg, pg, w0g, b0g, w1g, b1g, w2g, b2g, outg);
}